// Round 5
// baseline (265.696 us; speedup 1.0000x reference)
//
#include <hip/hip_runtime.h>
#include <hip/hip_bf16.h>
#include <math.h>

#define C_N 50000

typedef float f32x16 __attribute__((ext_vector_type(16)));
typedef float f32x4v __attribute__((ext_vector_type(4)));
typedef short bf16x8 __attribute__((ext_vector_type(8)));
#define VZERO16 {0.f,0.f,0.f,0.f,0.f,0.f,0.f,0.f,0.f,0.f,0.f,0.f,0.f,0.f,0.f,0.f}

// ---- ws layout (float offsets, all multiples of 16) ----
#define OQ     0        // Q[1024]
#define OS     1024     // S[16]
#define OZ     1040     // z[2048]
#define OH     3088     // hbuf[1024]
#define OY     4112     // ybuf[1024]
#define OP     5136     // Pu[16][1024] UNnormalized pooled nodes
#define OSUMB  21520    // per-block head sums 1024*16
#define OQK    37904    // qk[1024][16] fp32
#define OQKB   54288    // qkb bf16 B-fragments: 32 chunks*64 lanes*8 = 16384 bf16
#define OPP2   62480    // 2nd-level pool partials 64*16384
#define OPP    1111056  // pool partials nb*16384

__device__ __forceinline__ int brev4(int l){
  return ((l&1)<<3)|((l&2)<<1)|((l&4)>>1)|((l&8)>>3);
}

// Sum 16 values (in an f32x16) over all 64 lanes (used only in hm_qk2).
__device__ __forceinline__ float vred16(f32x16 v, int lane){
  float send, got;
#define RS(A,B,M) \
  send = (lane&M)? v[A] : v[B]; \
  got  = __shfl_xor(send, M);   \
  v[A] = ((lane&M)? v[B] : v[A]) + got;
  RS(0,8,1) RS(1,9,1) RS(2,10,1) RS(3,11,1)
  RS(4,12,1) RS(5,13,1) RS(6,14,1) RS(7,15,1)
  RS(0,4,2) RS(1,5,2) RS(2,6,2) RS(3,7,2)
  RS(0,2,4) RS(1,3,4)
  RS(0,1,8)
#undef RS
  float t = v[0];
  t += __shfl_xor(t,16);
  t += __shfl_xor(t,32);
  return t;
}

// ---- one-shot 16-output matvec block: out_j = sum_i x[i]*W[i*1024+j] ----
template<int IN>
__device__ __forceinline__ float mv_dot(const float* __restrict__ W,
    const float* __restrict__ x, int tid, int jblk){
  __shared__ float xs[IN];
  __shared__ float red[16][17];
  for (int k=tid;k<IN;k+=256) xs[k]=x[k];
  __syncthreads();
  int jq = tid&15, iq = tid>>4;
  int j = jblk*16 + jq;
  float acc = 0.f;
#pragma unroll 8
  for (int i=iq;i<IN;i+=16)
    acc = fmaf(xs[i], W[(size_t)i*1024 + j], acc);
  red[iq][jq] = acc;
  __syncthreads();
  float s = 0.f;
  if (tid < 16){
#pragma unroll
    for (int ii=0;ii<16;ii++) s += red[ii][tid];
  }
  return s;
}

// Q = z_prev@Wq + bq; also copy z_prev into z[1024:2048]
__global__ __launch_bounds__(256) void hm_mvQ(const float* __restrict__ W,
    const float* __restrict__ x, const float* __restrict__ bq,
    float* __restrict__ Q, float* __restrict__ z){
  float s = mv_dot<1024>(W, x, threadIdx.x, blockIdx.x);
  int tid = threadIdx.x;
  int j0 = blockIdx.x*16;
  if (tid < 16){
    Q[j0+tid] = s + bq[j0+tid];
    z[1024 + j0 + tid] = x[j0 + tid];
  }
}

// qk[i][h] = sum_t Wk[i][h*64+t] * Q[h*64+t]; one wave per row i.
__global__ __launch_bounds__(256) void hm_qk2(const float* __restrict__ Wk,
    const float* __restrict__ Q, float* __restrict__ qk){
  __shared__ float qlds[1024];
  int tid = threadIdx.x;
  for (int k=tid;k<1024;k+=256) qlds[k]=Q[k];
  __syncthreads();
  int w = tid>>6, l = tid&63;
  int i = blockIdx.x*4 + w;
  const float* wr = Wk + (size_t)i*1024 + l;
  f32x16 acc = VZERO16;
#define QKS(k) acc[k] = wr[k*64] * qlds[k*64 + l];
  QKS(0) QKS(1) QKS(2) QKS(3) QKS(4) QKS(5) QKS(6) QKS(7)
  QKS(8) QKS(9) QKS(10) QKS(11) QKS(12) QKS(13) QKS(14) QKS(15)
#undef QKS
  float t = vred16(acc, l);
  if (l < 16) qk[i*16 + brev4(l)] = t;
}

// Pack qk into bf16 MFMA B-fragment order:
// qkb[((kc*64 + l)*8 + jj)] = bf16( qk[(kc*32 + (l>>4)*8 + jj)*16 + (l&15)] )
// so that in hm_fused, wave w / lane l loads chunk kc as one bf16x8 and it
// supplies B[k=(l>>4)*8+jj][n=l&15] for k-chunk (w*8+kc).
__global__ __launch_bounds__(256) void hm_qkb(const float* __restrict__ qk,
    unsigned short* __restrict__ qkb){
  int t = blockIdx.x*256 + threadIdx.x;      // 0..16383
  int kc = t>>9, l = (t>>3)&63, jj = t&7;
  int i = kc*32 + ((l>>4)<<3) + jj;
  float v = qk[i*16 + (l&15)];
  __hip_bfloat16 b = __float2bfloat16(v);
  qkb[t] = *(unsigned short*)&b;
}

// Fused scores(MFMA)+softmax-exp+pool. Per 16-row batch (cb):
//   phase1: D[16r][16h] = A(nodes bf16) x B(qk bf16) via 8x mfma_16x16x32
//           per wave (wave w owns k in [w*256, w*256+256)); cross-wave sum
//           of the 4 partial D's in LDS.
//   phase2: e = exp(s/8) into LDS.
//   phase3: pool accs a[j][h] += nodes[c][j]*e[c][h] fp32 (rows L2-hot).
// C/D layout (m89-verified): lane holds D[(l>>4)*4+i][l&15].
__global__ __launch_bounds__(256,4) void hm_fused(const float* __restrict__ nodes,
    const unsigned short* __restrict__ qkb, float* __restrict__ parts,
    float* __restrict__ sumpb){
  __shared__ float part[4][16][17];
  __shared__ float eb[16][16];
  const int tid = threadIdx.x, w = tid>>6, l = tid&63;
  const int rowA = l&15, kgrp = l>>4;
  const int r_ = tid>>4, h_ = tid&15;

  // B fragments for this wave's K-quarter: 8 chunks x bf16x8 (32 VGPRs)
  bf16x8 bq0,bq1,bq2,bq3,bq4,bq5,bq6,bq7;
  {
    const bf16x8* qb = (const bf16x8*)qkb;
    const int o = w*8*64 + l;
    bq0=qb[o]; bq1=qb[o+64]; bq2=qb[o+128]; bq3=qb[o+192];
    bq4=qb[o+256]; bq5=qb[o+320]; bq6=qb[o+384]; bq7=qb[o+448];
  }
  f32x16 a0 = VZERO16, a1 = VZERO16, a2 = VZERO16, a3 = VZERO16;
  float ssum = 0.f;
  const float4* n4 = (const float4*)nodes;

  for (int cb = blockIdx.x; cb < 3125; cb += gridDim.x){
    // ---- phase 1: MFMA scores ----
    f32x4v D0 = {0.f,0.f,0.f,0.f};
    f32x4v D1 = {0.f,0.f,0.f,0.f};
    const float* ap = nodes + ((size_t)(cb*16 + rowA))*1024 + w*256 + kgrp*8;
#define SCHUNK(kc, BQ, DD) { \
    float4 fa = *(const float4*)(ap + kc*32); \
    float4 fb = *(const float4*)(ap + kc*32 + 4); \
    bf16x8 av; \
    __hip_bfloat16 t0=__float2bfloat16(fa.x), t1=__float2bfloat16(fa.y); \
    __hip_bfloat16 t2=__float2bfloat16(fa.z), t3=__float2bfloat16(fa.w); \
    __hip_bfloat16 t4=__float2bfloat16(fb.x), t5=__float2bfloat16(fb.y); \
    __hip_bfloat16 t6=__float2bfloat16(fb.z), t7=__float2bfloat16(fb.w); \
    av[0]=*(short*)&t0; av[1]=*(short*)&t1; av[2]=*(short*)&t2; av[3]=*(short*)&t3; \
    av[4]=*(short*)&t4; av[5]=*(short*)&t5; av[6]=*(short*)&t6; av[7]=*(short*)&t7; \
    DD = __builtin_amdgcn_mfma_f32_16x16x32_bf16(av, BQ, DD, 0, 0, 0); }
    SCHUNK(0,bq0,D0) SCHUNK(1,bq1,D1) SCHUNK(2,bq2,D0) SCHUNK(3,bq3,D1)
    SCHUNK(4,bq4,D0) SCHUNK(5,bq5,D1) SCHUNK(6,bq6,D0) SCHUNK(7,bq7,D1)
#undef SCHUNK
#pragma unroll
    for (int i=0;i<4;i++) part[w][kgrp*4+i][rowA] = D0[i] + D1[i];
    __syncthreads();
    // ---- phase 2: exp ----
    {
      float s = part[0][r_][h_]+part[1][r_][h_]+part[2][r_][h_]+part[3][r_][h_];
      eb[r_][h_] = __expf(s * 0.125f);
    }
    __syncthreads();
    if (tid < 16){
#pragma unroll
      for (int rr=0;rr<16;rr++) ssum += eb[rr][tid];
    }
    // ---- phase 3: pool (fp32, rows L1/L2-hot) ----
    size_t base = (size_t)cb*4096 + w*64 + l;
    float4 cur = n4[base];
#pragma unroll 4
    for (int r=0;r<16;r++){
      float4 nv = cur;
      if (r < 15) cur = n4[base + (size_t)(r+1)*256];
      f32x16 u = *(const f32x16*)&eb[r][0];
      a0 += u*nv.x; a1 += u*nv.y; a2 += u*nv.z; a3 += u*nv.w;
    }
    __syncthreads();
  }
  float* p = parts + (size_t)blockIdx.x*16384 + w*256 + l*4;
#pragma unroll
  for (int h=0;h<16;h++){
    float4 o = make_float4(a0[h],a1[h],a2[h],a3[h]);
    *(float4*)(p + h*1024) = o;
  }
  if (tid < 16) sumpb[blockIdx.x*16 + tid] = ssum;
}

// S[h] = sum over blocks of sumpb
__global__ __launch_bounds__(256) void hm_sumfin(const float* __restrict__ sumpb,
    float* __restrict__ S, int nb){
  __shared__ float red[16][17];
  int t = threadIdx.x, h = t&15, g = t>>4;
  float s = 0.f;
  for (int b=g; b<nb; b+=16) s += sumpb[b*16 + h];
  red[g][h] = s;
  __syncthreads();
  if (t < 16){
    float v = 0.f;
#pragma unroll
    for (int gg=0; gg<16; gg++) v += red[gg][t];
    S[t] = v;
  }
}

// Stage A: pp2[y][j] = sum of 16 partials (fully parallel, BW-bound)
__global__ __launch_bounds__(256) void hm_predA(const float* __restrict__ parts,
    float* __restrict__ pp2, int nb){
  int j = blockIdx.x*256 + threadIdx.x;
  int b0 = blockIdx.y*16;
  int b1 = b0+16 < nb ? b0+16 : nb;
  float s = 0.f;
  for (int b=b0;b<b1;b++) s += parts[(size_t)b*16384 + j];
  pp2[(size_t)blockIdx.y*16384 + j] = s;
}

// Stage B: Pu[j] = sum_y pp2[y][j]   (unnormalized; 1/S folded into mvV)
__global__ __launch_bounds__(256) void hm_predB(const float* __restrict__ pp2,
    float* __restrict__ Pu, int ny){
  int j = blockIdx.x*256 + threadIdx.x;
  float s = 0.f;
  for (int y=0;y<ny;y++) s += pp2[(size_t)y*16384 + j];
  Pu[j] = s;
}

// z[j] = (Pu[h]·Wv[:,j])/S[h] + bv[j], h = j>>6
__global__ __launch_bounds__(256) void hm_mvV(const float* __restrict__ W,
    const float* __restrict__ Pu, const float* __restrict__ S,
    const float* __restrict__ bv, float* __restrict__ z){
  const int hh = blockIdx.x>>2;
  const float* x = Pu + (size_t)hh*1024;
  float s = mv_dot<1024>(W, x, threadIdx.x, blockIdx.x);
  int tid = threadIdx.x;
  if (tid < 16){
    int j = blockIdx.x*16 + tid;
    z[j] = s / S[hh] + bv[j];
  }
}

__global__ __launch_bounds__(256) void hm_mvW1(const float* __restrict__ W,
    const float* __restrict__ z, const float* __restrict__ b1,
    float* __restrict__ hbuf){
  float s = mv_dot<2048>(W, z, threadIdx.x, blockIdx.x);
  int tid = threadIdx.x;
  if (tid < 16){
    int j = blockIdx.x*16 + tid;
    float v = s + b1[j];
    hbuf[j] = 0.5f * v * (1.0f + erff(v * 0.70710678118654752f));
  }
}

__global__ __launch_bounds__(256) void hm_mvW2(const float* __restrict__ W,
    const float* __restrict__ hb, const float* __restrict__ b2,
    float* __restrict__ y){
  float s = mv_dot<1024>(W, hb, threadIdx.x, blockIdx.x);
  int tid = threadIdx.x;
  if (tid < 16){
    int j = blockIdx.x*16 + tid;
    y[j] = s + b2[j];
  }
}

__global__ __launch_bounds__(256) void hm_rms(const float* __restrict__ y,
    const float* __restrict__ scale, float* __restrict__ out){
  __shared__ float red[4];
  __shared__ float msv;
  int tid = threadIdx.x;
  float local = 0.f;
  for (int j=tid;j<1024;j+=256){ float t = y[j]; local = fmaf(t,t,local); }
#pragma unroll
  for (int m=1;m<64;m<<=1) local += __shfl_xor(local, m);
  if ((tid&63)==0) red[tid>>6] = local;
  __syncthreads();
  if (tid==0){
    float s = red[0]+red[1]+red[2]+red[3];
    msv = rsqrtf(s*(1.0f/1024.0f) + 1e-6f);
  }
  __syncthreads();
  float r = msv;
  for (int j=tid;j<1024;j+=256) out[j] = scale[j]*y[j]*r;
}

extern "C" void kernel_launch(void* const* d_in, const int* in_sizes, int n_in,
                              void* d_out, int out_size, void* d_ws, size_t ws_size,
                              hipStream_t stream){
  const float* nodes  = (const float*)d_in[0];
  const float* z_prev = (const float*)d_in[1];
  const float* Wq = (const float*)d_in[2];
  const float* bq = (const float*)d_in[3];
  const float* Wk = (const float*)d_in[4];
  // d_in[5] = bk — cancels in softmax, unused
  const float* Wv = (const float*)d_in[6];
  const float* bv = (const float*)d_in[7];
  const float* W1 = (const float*)d_in[8];
  const float* b1 = (const float*)d_in[9];
  const float* W2 = (const float*)d_in[10];
  const float* b2 = (const float*)d_in[11];
  const float* scale = (const float*)d_in[12];
  float* ws  = (float*)d_ws;
  float* out = (float*)d_out;

  float* Qv   = ws + OQ;
  float* Sv   = ws + OS;
  float* z    = ws + OZ;
  float* hbuf = ws + OH;
  float* ybuf = ws + OY;
  float* Pu   = ws + OP;
  float* sumb = ws + OSUMB;
  float* qk   = ws + OQK;
  unsigned short* qkb = (unsigned short*)(ws + OQKB);
  float* pp2  = ws + OPP2;
  float* pp   = ws + OPP;

  size_t wsf = ws_size/4;
  int nbp = 1;
  if (wsf > (size_t)(OPP + 16384)) nbp = (int)((wsf - OPP)/16384);
  if (nbp > 1024) nbp = 1024;
  if (nbp < 1) nbp = 1;
  int ny = (nbp + 15)/16;   // <= 64

  hm_mvQ   <<<64,  256, 0, stream>>>(Wq, z_prev, bq, Qv, z);
  hm_qk2   <<<256, 256, 0, stream>>>(Wk, Qv, qk);
  hm_qkb   <<<64,  256, 0, stream>>>(qk, qkb);
  hm_fused <<<nbp, 256, 0, stream>>>(nodes, qkb, pp, sumb);
  hm_sumfin<<<1,   256, 0, stream>>>(sumb, Sv, nbp);
  hm_predA <<<dim3(64,ny), 256, 0, stream>>>(pp, pp2, nbp);
  hm_predB <<<64,  256, 0, stream>>>(pp2, Pu, ny);
  hm_mvV   <<<64,  256, 0, stream>>>(Wv, Pu, Sv, bv, z);
  hm_mvW1  <<<64,  256, 0, stream>>>(W1, z, b1, hbuf);
  hm_mvW2  <<<64,  256, 0, stream>>>(W2, hbuf, b2, ybuf);
  hm_rms   <<<1,   256, 0, stream>>>(ybuf, scale, out);
}

// Round 6
// 125.995 us; speedup vs baseline: 2.1088x; 2.1088x over previous
//
#include <hip/hip_runtime.h>
#include <hip/hip_bf16.h>
#include <math.h>

#define C_N 50000

typedef float f32x16 __attribute__((ext_vector_type(16)));
typedef float f32x4v __attribute__((ext_vector_type(4)));
typedef short bf16x8 __attribute__((ext_vector_type(8)));
#define VZERO16 {0.f,0.f,0.f,0.f,0.f,0.f,0.f,0.f,0.f,0.f,0.f,0.f,0.f,0.f,0.f,0.f}

// ---- ws layout (float offsets, all multiples of 16) ----
#define OQ     0        // Q[1024]
#define OS     1024     // S[16]
#define OZ     1040     // z[2048]
#define OH     3088     // hbuf[1024]
#define OY     4112     // ybuf[1024]
#define OP     5136     // Pu[16][1024] UNnormalized pooled nodes
#define OSUMB  21520    // per-block head sums 512*16
#define OQK    29712    // qk[1024][16] fp32
#define OQKB   46096    // qkb bf16 B-fragments: 16384 bf16
#define OPP2   54288    // 2nd-level pool partials 32*16384
#define OPP    578576   // pool partials nb*16384

__device__ __forceinline__ int brev4(int l){
  return ((l&1)<<3)|((l&2)<<1)|((l&4)>>1)|((l&8)>>3);
}

// Sum 16 values (in an f32x16) over all 64 lanes (used only in hm_qk2).
__device__ __forceinline__ float vred16(f32x16 v, int lane){
  float send, got;
#define RS(A,B,M) \
  send = (lane&M)? v[A] : v[B]; \
  got  = __shfl_xor(send, M);   \
  v[A] = ((lane&M)? v[B] : v[A]) + got;
  RS(0,8,1) RS(1,9,1) RS(2,10,1) RS(3,11,1)
  RS(4,12,1) RS(5,13,1) RS(6,14,1) RS(7,15,1)
  RS(0,4,2) RS(1,5,2) RS(2,6,2) RS(3,7,2)
  RS(0,2,4) RS(1,3,4)
  RS(0,1,8)
#undef RS
  float t = v[0];
  t += __shfl_xor(t,16);
  t += __shfl_xor(t,32);
  return t;
}

// ---- one-shot 16-output matvec block: out_j = sum_i x[i]*W[i*1024+j] ----
template<int IN>
__device__ __forceinline__ float mv_dot(const float* __restrict__ W,
    const float* __restrict__ x, int tid, int jblk){
  __shared__ float xs[IN];
  __shared__ float red[16][17];
  for (int k=tid;k<IN;k+=256) xs[k]=x[k];
  __syncthreads();
  int jq = tid&15, iq = tid>>4;
  int j = jblk*16 + jq;
  float acc = 0.f;
#pragma unroll 8
  for (int i=iq;i<IN;i+=16)
    acc = fmaf(xs[i], W[(size_t)i*1024 + j], acc);
  red[iq][jq] = acc;
  __syncthreads();
  float s = 0.f;
  if (tid < 16){
#pragma unroll
    for (int ii=0;ii<16;ii++) s += red[ii][tid];
  }
  return s;
}

// Q = z_prev@Wq + bq; also copy z_prev into z[1024:2048]
__global__ __launch_bounds__(256) void hm_mvQ(const float* __restrict__ W,
    const float* __restrict__ x, const float* __restrict__ bq,
    float* __restrict__ Q, float* __restrict__ z){
  float s = mv_dot<1024>(W, x, threadIdx.x, blockIdx.x);
  int tid = threadIdx.x;
  int j0 = blockIdx.x*16;
  if (tid < 16){
    Q[j0+tid] = s + bq[j0+tid];
    z[1024 + j0 + tid] = x[j0 + tid];
  }
}

// qk[i][h] = sum_t Wk[i][h*64+t] * Q[h*64+t]; one wave per row i.
__global__ __launch_bounds__(256) void hm_qk2(const float* __restrict__ Wk,
    const float* __restrict__ Q, float* __restrict__ qk){
  __shared__ float qlds[1024];
  int tid = threadIdx.x;
  for (int k=tid;k<1024;k+=256) qlds[k]=Q[k];
  __syncthreads();
  int w = tid>>6, l = tid&63;
  int i = blockIdx.x*4 + w;
  const float* wr = Wk + (size_t)i*1024 + l;
  f32x16 acc = VZERO16;
#define QKS(k) acc[k] = wr[k*64] * qlds[k*64 + l];
  QKS(0) QKS(1) QKS(2) QKS(3) QKS(4) QKS(5) QKS(6) QKS(7)
  QKS(8) QKS(9) QKS(10) QKS(11) QKS(12) QKS(13) QKS(14) QKS(15)
#undef QKS
  float t = vred16(acc, l);
  if (l < 16) qk[i*16 + brev4(l)] = t;
}

// Pack qk into bf16 MFMA B-fragment order:
// qkb[((kc*64 + l)*8 + jj)] = bf16( qk[(kc*32 + (l>>4)*8 + jj)*16 + (l&15)] )
__global__ __launch_bounds__(256) void hm_qkb(const float* __restrict__ qk,
    unsigned short* __restrict__ qkb){
  int t = blockIdx.x*256 + threadIdx.x;      // 0..16383
  int kc = t>>9, l = (t>>3)&63, jj = t&7;
  int i = kc*32 + ((l>>4)<<3) + jj;
  float v = qk[i*16 + (l&15)];
  __hip_bfloat16 b = __float2bfloat16(v);
  qkb[t] = *(unsigned short*)&b;
}

// Fused scores(MFMA)+softmax-exp+pool. Per 16-row batch (cb):
//   phase1: D[16r][16h] = A(nodes bf16) x B(qk bf16) via 8x mfma_16x16x32
//           per wave; cross-wave sum of the 4 partial D's in LDS.
//   phase2: e = exp(s/8) into LDS.
//   phase3: pool accs a[j][h] += nodes[c][j]*e[c][h] fp32 (rows L2-hot).
// launch_bounds(256,2): live state ~140-180 VGPR (32 B-frags + 64 pool accs
// + D + temps). The (256,4)=128-cap version SPILLED the pool accumulators
// (VGPR=64, 243MB scratch writes, 183us). 256-cap -> zero spill, 2 blocks/CU.
__global__ __launch_bounds__(256,2) void hm_fused(const float* __restrict__ nodes,
    const unsigned short* __restrict__ qkb, float* __restrict__ parts,
    float* __restrict__ sumpb){
  __shared__ float part[4][16][17];
  __shared__ float eb[16][16];
  const int tid = threadIdx.x, w = tid>>6, l = tid&63;
  const int rowA = l&15, kgrp = l>>4;
  const int r_ = tid>>4, h_ = tid&15;

  // B fragments for this wave's K-quarter: 8 chunks x bf16x8 (32 VGPRs)
  bf16x8 bq0,bq1,bq2,bq3,bq4,bq5,bq6,bq7;
  {
    const bf16x8* qb = (const bf16x8*)qkb;
    const int o = w*8*64 + l;
    bq0=qb[o]; bq1=qb[o+64]; bq2=qb[o+128]; bq3=qb[o+192];
    bq4=qb[o+256]; bq5=qb[o+320]; bq6=qb[o+384]; bq7=qb[o+448];
  }
  f32x16 a0 = VZERO16, a1 = VZERO16, a2 = VZERO16, a3 = VZERO16;
  float ssum = 0.f;
  const float4* n4 = (const float4*)nodes;

  for (int cb = blockIdx.x; cb < 3125; cb += gridDim.x){
    // ---- phase 1: MFMA scores ----
    f32x4v D0 = {0.f,0.f,0.f,0.f};
    f32x4v D1 = {0.f,0.f,0.f,0.f};
    const float* ap = nodes + ((size_t)(cb*16 + rowA))*1024 + w*256 + kgrp*8;
#define SCHUNK(kc, BQ, DD) { \
    float4 fa = *(const float4*)(ap + kc*32); \
    float4 fb = *(const float4*)(ap + kc*32 + 4); \
    bf16x8 av; \
    __hip_bfloat16 t0=__float2bfloat16(fa.x), t1=__float2bfloat16(fa.y); \
    __hip_bfloat16 t2=__float2bfloat16(fa.z), t3=__float2bfloat16(fa.w); \
    __hip_bfloat16 t4=__float2bfloat16(fb.x), t5=__float2bfloat16(fb.y); \
    __hip_bfloat16 t6=__float2bfloat16(fb.z), t7=__float2bfloat16(fb.w); \
    av[0]=*(short*)&t0; av[1]=*(short*)&t1; av[2]=*(short*)&t2; av[3]=*(short*)&t3; \
    av[4]=*(short*)&t4; av[5]=*(short*)&t5; av[6]=*(short*)&t6; av[7]=*(short*)&t7; \
    DD = __builtin_amdgcn_mfma_f32_16x16x32_bf16(av, BQ, DD, 0, 0, 0); }
    SCHUNK(0,bq0,D0) SCHUNK(1,bq1,D1) SCHUNK(2,bq2,D0) SCHUNK(3,bq3,D1)
    SCHUNK(4,bq4,D0) SCHUNK(5,bq5,D1) SCHUNK(6,bq6,D0) SCHUNK(7,bq7,D1)
#undef SCHUNK
#pragma unroll
    for (int i=0;i<4;i++) part[w][kgrp*4+i][rowA] = D0[i] + D1[i];
    __syncthreads();
    // ---- phase 2: exp ----
    {
      float s = part[0][r_][h_]+part[1][r_][h_]+part[2][r_][h_]+part[3][r_][h_];
      eb[r_][h_] = __expf(s * 0.125f);
    }
    __syncthreads();
    if (tid < 16){
#pragma unroll
      for (int rr=0;rr<16;rr++) ssum += eb[rr][tid];
    }
    // ---- phase 3: pool (fp32, rows L1/L2-hot) ----
    size_t base = (size_t)cb*4096 + w*64 + l;
    float4 cur = n4[base];
#pragma unroll 4
    for (int r=0;r<16;r++){
      float4 nv = cur;
      if (r < 15) cur = n4[base + (size_t)(r+1)*256];
      f32x16 u = *(const f32x16*)&eb[r][0];
      a0 += u*nv.x; a1 += u*nv.y; a2 += u*nv.z; a3 += u*nv.w;
    }
    __syncthreads();
  }
  float* p = parts + (size_t)blockIdx.x*16384 + w*256 + l*4;
#pragma unroll
  for (int h=0;h<16;h++){
    float4 o = make_float4(a0[h],a1[h],a2[h],a3[h]);
    *(float4*)(p + h*1024) = o;
  }
  if (tid < 16) sumpb[blockIdx.x*16 + tid] = ssum;
}

// S[h] = sum over blocks of sumpb
__global__ __launch_bounds__(256) void hm_sumfin(const float* __restrict__ sumpb,
    float* __restrict__ S, int nb){
  __shared__ float red[16][17];
  int t = threadIdx.x, h = t&15, g = t>>4;
  float s = 0.f;
  for (int b=g; b<nb; b+=16) s += sumpb[b*16 + h];
  red[g][h] = s;
  __syncthreads();
  if (t < 16){
    float v = 0.f;
#pragma unroll
    for (int gg=0; gg<16; gg++) v += red[gg][t];
    S[t] = v;
  }
}

// Stage A: pp2[y][j] = sum of 16 partials (fully parallel, BW-bound)
__global__ __launch_bounds__(256) void hm_predA(const float* __restrict__ parts,
    float* __restrict__ pp2, int nb){
  int j = blockIdx.x*256 + threadIdx.x;
  int b0 = blockIdx.y*16;
  int b1 = b0+16 < nb ? b0+16 : nb;
  float s = 0.f;
  for (int b=b0;b<b1;b++) s += parts[(size_t)b*16384 + j];
  pp2[(size_t)blockIdx.y*16384 + j] = s;
}

// Stage B: Pu[j] = sum_y pp2[y][j]   (unnormalized; 1/S folded into mvV)
__global__ __launch_bounds__(256) void hm_predB(const float* __restrict__ pp2,
    float* __restrict__ Pu, int ny){
  int j = blockIdx.x*256 + threadIdx.x;
  float s = 0.f;
  for (int y=0;y<ny;y++) s += pp2[(size_t)y*16384 + j];
  Pu[j] = s;
}

// z[j] = (Pu[h]·Wv[:,j])/S[h] + bv[j], h = j>>6
__global__ __launch_bounds__(256) void hm_mvV(const float* __restrict__ W,
    const float* __restrict__ Pu, const float* __restrict__ S,
    const float* __restrict__ bv, float* __restrict__ z){
  const int hh = blockIdx.x>>2;
  const float* x = Pu + (size_t)hh*1024;
  float s = mv_dot<1024>(W, x, threadIdx.x, blockIdx.x);
  int tid = threadIdx.x;
  if (tid < 16){
    int j = blockIdx.x*16 + tid;
    z[j] = s / S[hh] + bv[j];
  }
}

__global__ __launch_bounds__(256) void hm_mvW1(const float* __restrict__ W,
    const float* __restrict__ z, const float* __restrict__ b1,
    float* __restrict__ hbuf){
  float s = mv_dot<2048>(W, z, threadIdx.x, blockIdx.x);
  int tid = threadIdx.x;
  if (tid < 16){
    int j = blockIdx.x*16 + tid;
    float v = s + b1[j];
    hbuf[j] = 0.5f * v * (1.0f + erff(v * 0.70710678118654752f));
  }
}

__global__ __launch_bounds__(256) void hm_mvW2(const float* __restrict__ W,
    const float* __restrict__ hb, const float* __restrict__ b2,
    float* __restrict__ y){
  float s = mv_dot<1024>(W, hb, threadIdx.x, blockIdx.x);
  int tid = threadIdx.x;
  if (tid < 16){
    int j = blockIdx.x*16 + tid;
    y[j] = s + b2[j];
  }
}

__global__ __launch_bounds__(256) void hm_rms(const float* __restrict__ y,
    const float* __restrict__ scale, float* __restrict__ out){
  __shared__ float red[4];
  __shared__ float msv;
  int tid = threadIdx.x;
  float local = 0.f;
  for (int j=tid;j<1024;j+=256){ float t = y[j]; local = fmaf(t,t,local); }
#pragma unroll
  for (int m=1;m<64;m<<=1) local += __shfl_xor(local, m);
  if ((tid&63)==0) red[tid>>6] = local;
  __syncthreads();
  if (tid==0){
    float s = red[0]+red[1]+red[2]+red[3];
    msv = rsqrtf(s*(1.0f/1024.0f) + 1e-6f);
  }
  __syncthreads();
  float r = msv;
  for (int j=tid;j<1024;j+=256) out[j] = scale[j]*y[j]*r;
}

extern "C" void kernel_launch(void* const* d_in, const int* in_sizes, int n_in,
                              void* d_out, int out_size, void* d_ws, size_t ws_size,
                              hipStream_t stream){
  const float* nodes  = (const float*)d_in[0];
  const float* z_prev = (const float*)d_in[1];
  const float* Wq = (const float*)d_in[2];
  const float* bq = (const float*)d_in[3];
  const float* Wk = (const float*)d_in[4];
  // d_in[5] = bk — cancels in softmax, unused
  const float* Wv = (const float*)d_in[6];
  const float* bv = (const float*)d_in[7];
  const float* W1 = (const float*)d_in[8];
  const float* b1 = (const float*)d_in[9];
  const float* W2 = (const float*)d_in[10];
  const float* b2 = (const float*)d_in[11];
  const float* scale = (const float*)d_in[12];
  float* ws  = (float*)d_ws;
  float* out = (float*)d_out;

  float* Qv   = ws + OQ;
  float* Sv   = ws + OS;
  float* z    = ws + OZ;
  float* hbuf = ws + OH;
  float* ybuf = ws + OY;
  float* Pu   = ws + OP;
  float* sumb = ws + OSUMB;
  float* qk   = ws + OQK;
  unsigned short* qkb = (unsigned short*)(ws + OQKB);
  float* pp2  = ws + OPP2;
  float* pp   = ws + OPP;

  size_t wsf = ws_size/4;
  int nbp = 1;
  if (wsf > (size_t)(OPP + 16384)) nbp = (int)((wsf - OPP)/16384);
  if (nbp > 512) nbp = 512;
  if (nbp < 1) nbp = 1;
  int ny = (nbp + 15)/16;   // <= 32

  hm_mvQ   <<<64,  256, 0, stream>>>(Wq, z_prev, bq, Qv, z);
  hm_qk2   <<<256, 256, 0, stream>>>(Wk, Qv, qk);
  hm_qkb   <<<64,  256, 0, stream>>>(qk, qkb);
  hm_fused <<<nbp, 256, 0, stream>>>(nodes, qkb, pp, sumb);
  hm_sumfin<<<1,   256, 0, stream>>>(sumb, Sv, nbp);
  hm_predA <<<dim3(64,ny), 256, 0, stream>>>(pp, pp2, nbp);
  hm_predB <<<64,  256, 0, stream>>>(pp2, Pu, ny);
  hm_mvV   <<<64,  256, 0, stream>>>(Wv, Pu, Sv, bv, z);
  hm_mvW1  <<<64,  256, 0, stream>>>(W1, z, b1, hbuf);
  hm_mvW2  <<<64,  256, 0, stream>>>(W2, hbuf, b2, ybuf);
  hm_rms   <<<1,   256, 0, stream>>>(ybuf, scale, out);
}

// Round 7
// 114.172 us; speedup vs baseline: 2.3272x; 1.1035x over previous
//
#include <hip/hip_runtime.h>
#include <hip/hip_bf16.h>
#include <math.h>

#define C_N 50000

typedef float f32x16 __attribute__((ext_vector_type(16)));
typedef float f32x4v __attribute__((ext_vector_type(4)));
typedef short bf16x8 __attribute__((ext_vector_type(8)));
#define VZERO16 {0.f,0.f,0.f,0.f,0.f,0.f,0.f,0.f,0.f,0.f,0.f,0.f,0.f,0.f,0.f,0.f}

// ---- ws layout (float offsets, all multiples of 16) ----
#define OQ     0        // Q[1024]
#define OZ     1024     // z[2048]
#define OH     3072     // hbuf[1024]
#define OY     4096     // ybuf[1024]
#define OP     5120     // Pu[16][1024] UNnormalized pooled nodes
#define OSUMB  21504    // per-block head sums 512*16
#define OQKB   29696    // qkb bf16 B-fragments: 16384 bf16 (8192 floats)
#define OPP2   37888    // 2nd-level pool partials 32*16384
#define OPP    562176   // pool partials nb*16384

__device__ __forceinline__ int brev4(int l){
  return ((l&1)<<3)|((l&2)<<1)|((l&4)>>1)|((l&8)>>3);
}

// Sum 16 values (f32x16) over 64 lanes; lanes l<16 get total for head brev4(l).
__device__ __forceinline__ float vred16(f32x16 v, int lane){
  float send, got;
#define RS(A,B,M) \
  send = (lane&M)? v[A] : v[B]; \
  got  = __shfl_xor(send, M);   \
  v[A] = ((lane&M)? v[B] : v[A]) + got;
  RS(0,8,1) RS(1,9,1) RS(2,10,1) RS(3,11,1)
  RS(4,12,1) RS(5,13,1) RS(6,14,1) RS(7,15,1)
  RS(0,4,2) RS(1,5,2) RS(2,6,2) RS(3,7,2)
  RS(0,2,4) RS(1,3,4)
  RS(0,1,8)
#undef RS
  float t = v[0];
  t += __shfl_xor(t,16);
  t += __shfl_xor(t,32);
  return t;
}

// ---- 16-output matvec block, 512 threads: out_j = sum_i x[i]*W[i*1024+j] ----
template<int IN>
__device__ __forceinline__ float mv_dot(const float* __restrict__ W,
    const float* __restrict__ x, int tid, int jblk){
  __shared__ float xs[IN];
  __shared__ float red[32][17];
  for (int k=tid;k<IN;k+=512) xs[k]=x[k];
  __syncthreads();
  int jq = tid&15, iq = tid>>4;        // 32 i-groups x 16 j
  int j = jblk*16 + jq;
  float acc = 0.f;
#pragma unroll 8
  for (int i=iq;i<IN;i+=32)
    acc = fmaf(xs[i], W[(size_t)i*1024 + j], acc);
  red[iq][jq] = acc;
  __syncthreads();
  float s = 0.f;
  if (tid < 16){
#pragma unroll
    for (int ii=0;ii<32;ii++) s += red[ii][tid];
  }
  return s;
}

// Q = z_prev@Wq + bq; also copy z_prev into z[1024:2048]
__global__ __launch_bounds__(512) void hm_mvQ(const float* __restrict__ W,
    const float* __restrict__ x, const float* __restrict__ bq,
    float* __restrict__ Q, float* __restrict__ z){
  float s = mv_dot<1024>(W, x, threadIdx.x, blockIdx.x);
  int tid = threadIdx.x;
  int j0 = blockIdx.x*16;
  if (tid < 16){
    Q[j0+tid] = s + bq[j0+tid];
    z[1024 + j0 + tid] = x[j0 + tid];
  }
}

// qk[i][h] = sum_t Wk[i][h*64+t]*Q[h*64+t]; one wave per row i.
// Writes DIRECTLY in bf16 MFMA B-fragment order (merged old hm_qkb):
// flat bf16 idx = (kc*64 + rg*16 + h)*8 + jj with kc=i>>5, rg=(i>>3)&3, jj=i&7.
__global__ __launch_bounds__(256) void hm_qk2(const float* __restrict__ Wk,
    const float* __restrict__ Q, unsigned short* __restrict__ qkb){
  __shared__ float qlds[1024];
  int tid = threadIdx.x;
  for (int k=tid;k<1024;k+=256) qlds[k]=Q[k];
  __syncthreads();
  int w = tid>>6, l = tid&63;
  int i = blockIdx.x*4 + w;
  const float* wr = Wk + (size_t)i*1024 + l;
  f32x16 acc = VZERO16;
#define QKS(k) acc[k] = wr[k*64] * qlds[k*64 + l];
  QKS(0) QKS(1) QKS(2) QKS(3) QKS(4) QKS(5) QKS(6) QKS(7)
  QKS(8) QKS(9) QKS(10) QKS(11) QKS(12) QKS(13) QKS(14) QKS(15)
#undef QKS
  float t = vred16(acc, l);
  if (l < 16){
    int h = brev4(l);
    int kc = i>>5, rg = (i>>3)&3, jj = i&7;
    __hip_bfloat16 b = __float2bfloat16(t);
    qkb[(kc*64 + rg*16 + h)*8 + jj] = *(unsigned short*)&b;
  }
}

#define LD2(AP,KC,FA,FB) \
  FA = *(const float4*)((AP)+(KC)*32); \
  FB = *(const float4*)((AP)+(KC)*32+4);
#define CVT8(FA,FB,AV) { \
  __hip_bfloat16 c0=__float2bfloat16(FA.x),c1=__float2bfloat16(FA.y); \
  __hip_bfloat16 c2=__float2bfloat16(FA.z),c3=__float2bfloat16(FA.w); \
  __hip_bfloat16 c4=__float2bfloat16(FB.x),c5=__float2bfloat16(FB.y); \
  __hip_bfloat16 c6=__float2bfloat16(FB.z),c7=__float2bfloat16(FB.w); \
  AV[0]=*(short*)&c0; AV[1]=*(short*)&c1; AV[2]=*(short*)&c2; AV[3]=*(short*)&c3; \
  AV[4]=*(short*)&c4; AV[5]=*(short*)&c5; AV[6]=*(short*)&c6; AV[7]=*(short*)&c7; }

// Fused scores(MFMA)+exp+pool, software-pipelined:
//   preload cb0 frags; each iter: MFMA(cb) -> issue fp32 loads for cb+stride
//   -> LDS reduce -> exp -> pool(cb, rows L2-hot) -> convert prefetched to bf16.
// 2 barriers/cb (end-of-pool barrier provably removable: next-iter part writes
// never race eb reads; eb rewrites are fenced by the next ph1-end barrier).
// launch_bounds(256,2): live ~200 VGPR (bq32+accs64+prefetch64+av32). The
// 128-cap version spilled accs (243MB scratch, 183us) — keep 256 cap.
__global__ __launch_bounds__(256,2) void hm_fused(const float* __restrict__ nodes,
    const unsigned short* __restrict__ qkb, float* __restrict__ parts,
    float* __restrict__ sumpb){
  __shared__ float part[4][16][17];
  __shared__ float eb[16][16];
  const int tid = threadIdx.x, w = tid>>6, l = tid&63;
  const int rowA = l&15, kgrp = l>>4;
  const int r_ = tid>>4, h_ = tid&15;

  bf16x8 bq0,bq1,bq2,bq3,bq4,bq5,bq6,bq7;
  {
    const bf16x8* qb = (const bf16x8*)qkb;
    const int o = w*8*64 + l;
    bq0=qb[o]; bq1=qb[o+64]; bq2=qb[o+128]; bq3=qb[o+192];
    bq4=qb[o+256]; bq5=qb[o+320]; bq6=qb[o+384]; bq7=qb[o+448];
  }
  f32x16 a0 = VZERO16, a1 = VZERO16, a2 = VZERO16, a3 = VZERO16;
  float ssum = 0.f;
  const float4* n4 = (const float4*)nodes;
  const int stride = gridDim.x;

  int cb = blockIdx.x;
  float4 p0a,p0b,p1a,p1b,p2a,p2b,p3a,p3b,p4a,p4b,p5a,p5b,p6a,p6b,p7a,p7b;
  {
    const float* ap = nodes + ((size_t)(cb*16 + rowA))*1024 + w*256 + kgrp*8;
    LD2(ap,0,p0a,p0b) LD2(ap,1,p1a,p1b) LD2(ap,2,p2a,p2b) LD2(ap,3,p3a,p3b)
    LD2(ap,4,p4a,p4b) LD2(ap,5,p5a,p5b) LD2(ap,6,p6a,p6b) LD2(ap,7,p7a,p7b)
  }
  bf16x8 av0,av1,av2,av3,av4,av5,av6,av7;
  CVT8(p0a,p0b,av0) CVT8(p1a,p1b,av1) CVT8(p2a,p2b,av2) CVT8(p3a,p3b,av3)
  CVT8(p4a,p4b,av4) CVT8(p5a,p5b,av5) CVT8(p6a,p6b,av6) CVT8(p7a,p7b,av7)

  for (; cb < 3125; cb += stride){
    // ---- phase 1: MFMA scores for cb ----
    f32x4v D0 = {0.f,0.f,0.f,0.f};
    f32x4v D1 = {0.f,0.f,0.f,0.f};
    D0 = __builtin_amdgcn_mfma_f32_16x16x32_bf16(av0, bq0, D0, 0,0,0);
    D1 = __builtin_amdgcn_mfma_f32_16x16x32_bf16(av1, bq1, D1, 0,0,0);
    D0 = __builtin_amdgcn_mfma_f32_16x16x32_bf16(av2, bq2, D0, 0,0,0);
    D1 = __builtin_amdgcn_mfma_f32_16x16x32_bf16(av3, bq3, D1, 0,0,0);
    D0 = __builtin_amdgcn_mfma_f32_16x16x32_bf16(av4, bq4, D0, 0,0,0);
    D1 = __builtin_amdgcn_mfma_f32_16x16x32_bf16(av5, bq5, D1, 0,0,0);
    D0 = __builtin_amdgcn_mfma_f32_16x16x32_bf16(av6, bq6, D0, 0,0,0);
    D1 = __builtin_amdgcn_mfma_f32_16x16x32_bf16(av7, bq7, D1, 0,0,0);
    // ---- issue next-cb fragment loads (overlap ph2+ph3) ----
    {
      int cbn = cb + stride; if (cbn >= 3125) cbn = cb;
      const float* apn = nodes + ((size_t)(cbn*16 + rowA))*1024 + w*256 + kgrp*8;
      LD2(apn,0,p0a,p0b) LD2(apn,1,p1a,p1b) LD2(apn,2,p2a,p2b) LD2(apn,3,p3a,p3b)
      LD2(apn,4,p4a,p4b) LD2(apn,5,p5a,p5b) LD2(apn,6,p6a,p6b) LD2(apn,7,p7a,p7b)
    }
#pragma unroll
    for (int i=0;i<4;i++) part[w][kgrp*4+i][rowA] = D0[i] + D1[i];
    __syncthreads();
    // ---- phase 2: exp ----
    {
      float s = part[0][r_][h_]+part[1][r_][h_]+part[2][r_][h_]+part[3][r_][h_];
      eb[r_][h_] = __expf(s * 0.125f);
    }
    __syncthreads();
    if (tid < 16){
#pragma unroll
      for (int rr=0;rr<16;rr++) ssum += eb[rr][tid];
    }
    // ---- phase 3: pool (fp32, rows L2-hot) ----
    size_t base = (size_t)cb*4096 + w*64 + l;
    float4 cur = n4[base];
#pragma unroll 4
    for (int r=0;r<16;r++){
      float4 nv = cur;
      if (r < 15) cur = n4[base + (size_t)(r+1)*256];
      f32x16 u = *(const f32x16*)&eb[r][0];
      a0 += u*nv.x; a1 += u*nv.y; a2 += u*nv.z; a3 += u*nv.w;
    }
    // ---- convert prefetched fp32 -> bf16 frags (loads have had ph2+ph3) ----
    CVT8(p0a,p0b,av0) CVT8(p1a,p1b,av1) CVT8(p2a,p2b,av2) CVT8(p3a,p3b,av3)
    CVT8(p4a,p4b,av4) CVT8(p5a,p5b,av5) CVT8(p6a,p6b,av6) CVT8(p7a,p7b,av7)
  }
  float* p = parts + (size_t)blockIdx.x*16384 + w*256 + l*4;
#pragma unroll
  for (int h=0;h<16;h++){
    float4 o = make_float4(a0[h],a1[h],a2[h],a3[h]);
    *(float4*)(p + h*1024) = o;
  }
  if (tid < 16) sumpb[blockIdx.x*16 + tid] = ssum;
}

// Stage A: pp2[y][j] = sum of 16 partials (fully parallel, BW-bound)
__global__ __launch_bounds__(256) void hm_predA(const float* __restrict__ parts,
    float* __restrict__ pp2, int nb){
  int j = blockIdx.x*256 + threadIdx.x;
  int b0 = blockIdx.y*16;
  int b1 = b0+16 < nb ? b0+16 : nb;
  float s = 0.f;
  for (int b=b0;b<b1;b++) s += parts[(size_t)b*16384 + j];
  pp2[(size_t)blockIdx.y*16384 + j] = s;
}

// Stage B: Pu[j] = sum_y pp2[y][j]   (unnormalized; 1/S folded into mvV)
__global__ __launch_bounds__(256) void hm_predB(const float* __restrict__ pp2,
    float* __restrict__ Pu, int ny){
  int j = blockIdx.x*256 + threadIdx.x;
  float s = 0.f;
  for (int y=0;y<ny;y++) s += pp2[(size_t)y*16384 + j];
  Pu[j] = s;
}

// z[j] = (Pu[h]·Wv[:,j])/S[h] + bv[j]; S[h] reduced inline from sumpb.
__global__ __launch_bounds__(512) void hm_mvV(const float* __restrict__ W,
    const float* __restrict__ Pu, const float* __restrict__ sumpb,
    const float* __restrict__ bv, float* __restrict__ z, int nb){
  __shared__ float ssl[8];
  const int tid = threadIdx.x;
  const int hh = blockIdx.x>>2;
  float sacc = 0.f;
  for (int b=tid; b<nb; b+=512) sacc += sumpb[b*16 + hh];
#pragma unroll
  for (int m=1;m<64;m<<=1) sacc += __shfl_xor(sacc, m);
  if ((tid&63)==0) ssl[tid>>6] = sacc;
  // mv_dot's internal barriers order ssl writes before the tid<16 read below
  const float* x = Pu + (size_t)hh*1024;
  float s = mv_dot<1024>(W, x, tid, blockIdx.x);
  if (tid < 16){
    float S = ssl[0]+ssl[1]+ssl[2]+ssl[3]+ssl[4]+ssl[5]+ssl[6]+ssl[7];
    int j = blockIdx.x*16 + tid;
    z[j] = s / S + bv[j];
  }
}

__global__ __launch_bounds__(512) void hm_mvW1(const float* __restrict__ W,
    const float* __restrict__ z, const float* __restrict__ b1,
    float* __restrict__ hbuf){
  float s = mv_dot<2048>(W, z, threadIdx.x, blockIdx.x);
  int tid = threadIdx.x;
  if (tid < 16){
    int j = blockIdx.x*16 + tid;
    float v = s + b1[j];
    hbuf[j] = 0.5f * v * (1.0f + erff(v * 0.70710678118654752f));
  }
}

__global__ __launch_bounds__(512) void hm_mvW2(const float* __restrict__ W,
    const float* __restrict__ hb, const float* __restrict__ b2,
    float* __restrict__ y){
  float s = mv_dot<1024>(W, hb, threadIdx.x, blockIdx.x);
  int tid = threadIdx.x;
  if (tid < 16){
    int j = blockIdx.x*16 + tid;
    y[j] = s + b2[j];
  }
}

__global__ __launch_bounds__(256) void hm_rms(const float* __restrict__ y,
    const float* __restrict__ scale, float* __restrict__ out){
  __shared__ float red[4];
  __shared__ float msv;
  int tid = threadIdx.x;
  float local = 0.f;
  for (int j=tid;j<1024;j+=256){ float t = y[j]; local = fmaf(t,t,local); }
#pragma unroll
  for (int m=1;m<64;m<<=1) local += __shfl_xor(local, m);
  if ((tid&63)==0) red[tid>>6] = local;
  __syncthreads();
  if (tid==0){
    float s = red[0]+red[1]+red[2]+red[3];
    msv = rsqrtf(s*(1.0f/1024.0f) + 1e-6f);
  }
  __syncthreads();
  float r = msv;
  for (int j=tid;j<1024;j+=256) out[j] = scale[j]*y[j]*r;
}

extern "C" void kernel_launch(void* const* d_in, const int* in_sizes, int n_in,
                              void* d_out, int out_size, void* d_ws, size_t ws_size,
                              hipStream_t stream){
  const float* nodes  = (const float*)d_in[0];
  const float* z_prev = (const float*)d_in[1];
  const float* Wq = (const float*)d_in[2];
  const float* bq = (const float*)d_in[3];
  const float* Wk = (const float*)d_in[4];
  // d_in[5] = bk — cancels in softmax, unused
  const float* Wv = (const float*)d_in[6];
  const float* bv = (const float*)d_in[7];
  const float* W1 = (const float*)d_in[8];
  const float* b1 = (const float*)d_in[9];
  const float* W2 = (const float*)d_in[10];
  const float* b2 = (const float*)d_in[11];
  const float* scale = (const float*)d_in[12];
  float* ws  = (float*)d_ws;
  float* out = (float*)d_out;

  float* Qv   = ws + OQ;
  float* z    = ws + OZ;
  float* hbuf = ws + OH;
  float* ybuf = ws + OY;
  float* Pu   = ws + OP;
  float* sumb = ws + OSUMB;
  unsigned short* qkb = (unsigned short*)(ws + OQKB);
  float* pp2  = ws + OPP2;
  float* pp   = ws + OPP;

  size_t wsf = ws_size/4;
  int nbp = 1;
  if (wsf > (size_t)(OPP + 16384)) nbp = (int)((wsf - OPP)/16384);
  if (nbp > 512) nbp = 512;
  if (nbp < 1) nbp = 1;
  int ny = (nbp + 15)/16;   // <= 32

  hm_mvQ   <<<64,  512, 0, stream>>>(Wq, z_prev, bq, Qv, z);
  hm_qk2   <<<256, 256, 0, stream>>>(Wk, Qv, qkb);
  hm_fused <<<nbp, 256, 0, stream>>>(nodes, qkb, pp, sumb);
  hm_predA <<<dim3(64,ny), 256, 0, stream>>>(pp, pp2, nbp);
  hm_predB <<<64,  256, 0, stream>>>(pp2, Pu, ny);
  hm_mvV   <<<64,  512, 0, stream>>>(Wv, Pu, sumb, bv, z, nbp);
  hm_mvW1  <<<64,  512, 0, stream>>>(W1, z, b1, hbuf);
  hm_mvW2  <<<64,  512, 0, stream>>>(W2, hbuf, b2, ybuf);
  hm_rms   <<<1,   256, 0, stream>>>(ybuf, scale, out);
}

// Round 8
// 102.081 us; speedup vs baseline: 2.6028x; 1.1184x over previous
//
#include <hip/hip_runtime.h>
#include <hip/hip_bf16.h>
#include <math.h>

#define C_N 50000

typedef float f32x16 __attribute__((ext_vector_type(16)));
typedef float f32x4v __attribute__((ext_vector_type(4)));
typedef short bf16x8 __attribute__((ext_vector_type(8)));
#define VZERO16 {0.f,0.f,0.f,0.f,0.f,0.f,0.f,0.f,0.f,0.f,0.f,0.f,0.f,0.f,0.f,0.f}

// ---- ws layout (float offsets, all multiples of 16) ----
#define OQ     0        // Q[1024]
#define OZ     1024     // z[2048]
#define OH     3072     // hbuf[1024]
#define OY     4096     // ybuf[1024]
#define OSUMB  5120     // per-block head sums 512*16
#define OQKB   13312    // qkb bf16 B-fragments: 16384 bf16 (8192 floats)
#define OPP2   21504    // 2nd-level pool partials 32*16384
#define OPP    545792   // pool partials nb*16384

__device__ __forceinline__ int brev4(int l){
  return ((l&1)<<3)|((l&2)<<1)|((l&4)>>1)|((l&8)>>3);
}

// Sum 16 values (f32x16) over 64 lanes; lanes l<16 get total for head brev4(l).
__device__ __forceinline__ float vred16(f32x16 v, int lane){
  float send, got;
#define RS(A,B,M) \
  send = (lane&M)? v[A] : v[B]; \
  got  = __shfl_xor(send, M);   \
  v[A] = ((lane&M)? v[B] : v[A]) + got;
  RS(0,8,1) RS(1,9,1) RS(2,10,1) RS(3,11,1)
  RS(4,12,1) RS(5,13,1) RS(6,14,1) RS(7,15,1)
  RS(0,4,2) RS(1,5,2) RS(2,6,2) RS(3,7,2)
  RS(0,2,4) RS(1,3,4)
  RS(0,1,8)
#undef RS
  float t = v[0];
  t += __shfl_xor(t,16);
  t += __shfl_xor(t,32);
  return t;
}

// ---- 16-output matvec block, 512 threads: out_j = sum_i x[i]*W[i*1024+j] ----
template<int IN>
__device__ __forceinline__ float mv_dot(const float* __restrict__ W,
    const float* __restrict__ x, int tid, int jblk){
  __shared__ float xs[IN];
  __shared__ float red[32][17];
  for (int k=tid;k<IN;k+=512) xs[k]=x[k];
  __syncthreads();
  int jq = tid&15, iq = tid>>4;        // 32 i-groups x 16 j
  int j = jblk*16 + jq;
  float acc = 0.f;
#pragma unroll 8
  for (int i=iq;i<IN;i+=32)
    acc = fmaf(xs[i], W[(size_t)i*1024 + j], acc);
  red[iq][jq] = acc;
  __syncthreads();
  float s = 0.f;
  if (tid < 16){
#pragma unroll
    for (int ii=0;ii<32;ii++) s += red[ii][tid];
  }
  return s;
}

// Q = z_prev@Wq + bq; also copy z_prev into z[1024:2048]
__global__ __launch_bounds__(512) void hm_mvQ(const float* __restrict__ W,
    const float* __restrict__ x, const float* __restrict__ bq,
    float* __restrict__ Q, float* __restrict__ z){
  float s = mv_dot<1024>(W, x, threadIdx.x, blockIdx.x);
  int tid = threadIdx.x;
  int j0 = blockIdx.x*16;
  if (tid < 16){
    Q[j0+tid] = s + bq[j0+tid];
    z[1024 + j0 + tid] = x[j0 + tid];
  }
}

// qk[i][h] = sum_t Wk[i][h*64+t]*Q[h*64+t]; one wave per row i.
// Writes DIRECTLY in bf16 MFMA B-fragment order:
// flat bf16 idx = (kc*64 + rg*16 + h)*8 + jj with kc=i>>5, rg=(i>>3)&3, jj=i&7.
__global__ __launch_bounds__(256) void hm_qk2(const float* __restrict__ Wk,
    const float* __restrict__ Q, unsigned short* __restrict__ qkb){
  __shared__ float qlds[1024];
  int tid = threadIdx.x;
  for (int k=tid;k<1024;k+=256) qlds[k]=Q[k];
  __syncthreads();
  int w = tid>>6, l = tid&63;
  int i = blockIdx.x*4 + w;
  const float* wr = Wk + (size_t)i*1024 + l;
  f32x16 acc = VZERO16;
#define QKS(k) acc[k] = wr[k*64] * qlds[k*64 + l];
  QKS(0) QKS(1) QKS(2) QKS(3) QKS(4) QKS(5) QKS(6) QKS(7)
  QKS(8) QKS(9) QKS(10) QKS(11) QKS(12) QKS(13) QKS(14) QKS(15)
#undef QKS
  float t = vred16(acc, l);
  if (l < 16){
    int h = brev4(l);
    int kc = i>>5, rg = (i>>3)&3, jj = i&7;
    __hip_bfloat16 b = __float2bfloat16(t);
    qkb[(kc*64 + rg*16 + h)*8 + jj] = *(unsigned short*)&b;
  }
}

#define LD2(AP,KC,FA,FB) \
  FA = *(const float4*)((AP)+(KC)*32); \
  FB = *(const float4*)((AP)+(KC)*32+4);
#define CVT8(FA,FB,AV) { \
  __hip_bfloat16 c0=__float2bfloat16(FA.x),c1=__float2bfloat16(FA.y); \
  __hip_bfloat16 c2=__float2bfloat16(FA.z),c3=__float2bfloat16(FA.w); \
  __hip_bfloat16 c4=__float2bfloat16(FB.x),c5=__float2bfloat16(FB.y); \
  __hip_bfloat16 c6=__float2bfloat16(FB.z),c7=__float2bfloat16(FB.w); \
  AV[0]=*(short*)&c0; AV[1]=*(short*)&c1; AV[2]=*(short*)&c2; AV[3]=*(short*)&c3; \
  AV[4]=*(short*)&c4; AV[5]=*(short*)&c5; AV[6]=*(short*)&c6; AV[7]=*(short*)&c7; }

// Fused scores(MFMA)+exp+pool with LDS tile staging (single nodes read):
// per cb: [barrier0] ds_write fp32 tile (from prefetch regs) -> av=bf16(p)
// -> 8 MFMA -> issue prefetch(cb+stride) -> part=D -> [barrier1] exp->eb
// -> [barrier2] pool from LDS tile (no global re-read).
// Tile [16][1028]: row stride 1028 == 4 (mod 32) makes the 64-lane write
// pattern (4*row+8*kgrp)%32 hit every bank with exactly 8 lanes = the 1KB/wave
// floor (8 cyc, optimal); reads are contiguous 1KB/wave (optimal).
// launch_bounds(256,2): live ~215 VGPR (p64+bq32+accs64+av32+misc). The
// 128-cap version spilled accs (243MB scratch, 183us) — keep 256 cap.
// LDS: 65792 dynamic + ~5.4KB static = 71KB/block; x2 blocks = 142KB <= 160KB.
__global__ __launch_bounds__(256,2) void hm_fused(const float* __restrict__ nodes,
    const unsigned short* __restrict__ qkb, float* __restrict__ parts,
    float* __restrict__ sumpb){
  extern __shared__ float tile[];           // [16][1028]
  __shared__ float part[4][16][17];
  __shared__ float eb[16][16];
  const int tid = threadIdx.x, w = tid>>6, l = tid&63;
  const int rowA = l&15, kgrp = l>>4;
  const int r_ = tid>>4, h_ = tid&15;

  bf16x8 bq0,bq1,bq2,bq3,bq4,bq5,bq6,bq7;
  {
    const bf16x8* qb = (const bf16x8*)qkb;
    const int o = w*8*64 + l;
    bq0=qb[o]; bq1=qb[o+64]; bq2=qb[o+128]; bq3=qb[o+192];
    bq4=qb[o+256]; bq5=qb[o+320]; bq6=qb[o+384]; bq7=qb[o+448];
  }
  f32x16 a0 = VZERO16, a1 = VZERO16, a2 = VZERO16, a3 = VZERO16;
  float ssum = 0.f;
  const int stride = gridDim.x;

  int cb = blockIdx.x;
  float4 p0a,p0b,p1a,p1b,p2a,p2b,p3a,p3b,p4a,p4b,p5a,p5b,p6a,p6b,p7a,p7b;
  {
    const float* ap = nodes + ((size_t)(cb*16 + rowA))*1024 + w*256 + kgrp*8;
    LD2(ap,0,p0a,p0b) LD2(ap,1,p1a,p1b) LD2(ap,2,p2a,p2b) LD2(ap,3,p3a,p3b)
    LD2(ap,4,p4a,p4b) LD2(ap,5,p5a,p5b) LD2(ap,6,p6a,p6b) LD2(ap,7,p7a,p7b)
  }
  // this lane's tile slot: row rowA, cols w*256 + kgrp*8 + kc*32
  float* tw = tile + rowA*1028 + w*256 + kgrp*8;

  for (; cb < 3125; cb += stride){
    // ---- barrier0: all waves done reading previous tile ----
    __syncthreads();
    // ---- park this cb's fp32 fragments in LDS (pool uses them later) ----
    *(float4*)(tw+0*32) = p0a; *(float4*)(tw+0*32+4) = p0b;
    *(float4*)(tw+1*32) = p1a; *(float4*)(tw+1*32+4) = p1b;
    *(float4*)(tw+2*32) = p2a; *(float4*)(tw+2*32+4) = p2b;
    *(float4*)(tw+3*32) = p3a; *(float4*)(tw+3*32+4) = p3b;
    *(float4*)(tw+4*32) = p4a; *(float4*)(tw+4*32+4) = p4b;
    *(float4*)(tw+5*32) = p5a; *(float4*)(tw+5*32+4) = p5b;
    *(float4*)(tw+6*32) = p6a; *(float4*)(tw+6*32+4) = p6b;
    *(float4*)(tw+7*32) = p7a; *(float4*)(tw+7*32+4) = p7b;
    // ---- phase 1: convert + MFMA scores ----
    bf16x8 av0,av1,av2,av3,av4,av5,av6,av7;
    CVT8(p0a,p0b,av0) CVT8(p1a,p1b,av1) CVT8(p2a,p2b,av2) CVT8(p3a,p3b,av3)
    CVT8(p4a,p4b,av4) CVT8(p5a,p5b,av5) CVT8(p6a,p6b,av6) CVT8(p7a,p7b,av7)
    f32x4v D0 = {0.f,0.f,0.f,0.f};
    f32x4v D1 = {0.f,0.f,0.f,0.f};
    D0 = __builtin_amdgcn_mfma_f32_16x16x32_bf16(av0, bq0, D0, 0,0,0);
    D1 = __builtin_amdgcn_mfma_f32_16x16x32_bf16(av1, bq1, D1, 0,0,0);
    D0 = __builtin_amdgcn_mfma_f32_16x16x32_bf16(av2, bq2, D0, 0,0,0);
    D1 = __builtin_amdgcn_mfma_f32_16x16x32_bf16(av3, bq3, D1, 0,0,0);
    D0 = __builtin_amdgcn_mfma_f32_16x16x32_bf16(av4, bq4, D0, 0,0,0);
    D1 = __builtin_amdgcn_mfma_f32_16x16x32_bf16(av5, bq5, D1, 0,0,0);
    D0 = __builtin_amdgcn_mfma_f32_16x16x32_bf16(av6, bq6, D0, 0,0,0);
    D1 = __builtin_amdgcn_mfma_f32_16x16x32_bf16(av7, bq7, D1, 0,0,0);
    // ---- issue next-cb fragment loads (land during ph2+ph3) ----
    {
      int cbn = cb + stride; if (cbn >= 3125) cbn = cb;
      const float* apn = nodes + ((size_t)(cbn*16 + rowA))*1024 + w*256 + kgrp*8;
      LD2(apn,0,p0a,p0b) LD2(apn,1,p1a,p1b) LD2(apn,2,p2a,p2b) LD2(apn,3,p3a,p3b)
      LD2(apn,4,p4a,p4b) LD2(apn,5,p5a,p5b) LD2(apn,6,p6a,p6b) LD2(apn,7,p7a,p7b)
    }
#pragma unroll
    for (int i=0;i<4;i++) part[w][kgrp*4+i][rowA] = D0[i] + D1[i];
    __syncthreads();                       // barrier1
    // ---- phase 2: exp ----
    {
      float s = part[0][r_][h_]+part[1][r_][h_]+part[2][r_][h_]+part[3][r_][h_];
      eb[r_][h_] = __expf(s * 0.125f);
    }
    __syncthreads();                       // barrier2
    if (tid < 16){
#pragma unroll
      for (int rr=0;rr<16;rr++) ssum += eb[rr][tid];
    }
    // ---- phase 3: pool from LDS tile (contiguous 1KB/wave reads) ----
    const float* tr = tile + w*256 + l*4;
#pragma unroll 4
    for (int r=0;r<16;r++){
      float4 nv = *(const float4*)(tr + r*1028);
      f32x16 u = *(const f32x16*)&eb[r][0];
      a0 += u*nv.x; a1 += u*nv.y; a2 += u*nv.z; a3 += u*nv.w;
    }
  }
  float* p = parts + (size_t)blockIdx.x*16384 + w*256 + l*4;
#pragma unroll
  for (int h=0;h<16;h++){
    float4 o = make_float4(a0[h],a1[h],a2[h],a3[h]);
    *(float4*)(p + h*1024) = o;
  }
  if (tid < 16) sumpb[blockIdx.x*16 + tid] = ssum;
}

// Stage A: pp2[y][j] = sum of 16 partials (fully parallel, BW-bound)
__global__ __launch_bounds__(256) void hm_predA(const float* __restrict__ parts,
    float* __restrict__ pp2, int nb){
  int j = blockIdx.x*256 + threadIdx.x;
  int b0 = blockIdx.y*16;
  int b1 = b0+16 < nb ? b0+16 : nb;
  float s = 0.f;
  for (int b=b0;b<b1;b++) s += parts[(size_t)b*16384 + j];
  pp2[(size_t)blockIdx.y*16384 + j] = s;
}

// z[j] = (Pu[h]·Wv[:,j])/S[h] + bv[j]; Pu row hh summed from pp2 in-kernel
// (predB merged); S[h] reduced inline from sumpb.
__global__ __launch_bounds__(512) void hm_mvV(const float* __restrict__ W,
    const float* __restrict__ pp2, const float* __restrict__ sumpb,
    const float* __restrict__ bv, float* __restrict__ z, int ny, int nb){
  __shared__ float xs[1024];
  __shared__ float red[32][17];
  __shared__ float ssl[8];
  const int tid = threadIdx.x;
  const int hh = blockIdx.x>>2;
  float sacc = 0.f;
  for (int b=tid; b<nb; b+=512) sacc += sumpb[b*16 + hh];
#pragma unroll
  for (int m=1;m<64;m<<=1) sacc += __shfl_xor(sacc, m);
  if ((tid&63)==0) ssl[tid>>6] = sacc;
  for (int k=tid;k<1024;k+=512){
    float s = 0.f;
    for (int y=0;y<ny;y++) s += pp2[(size_t)y*16384 + hh*1024 + k];
    xs[k] = s;
  }
  __syncthreads();
  int jq = tid&15, iq = tid>>4;
  int j = blockIdx.x*16 + jq;
  float acc = 0.f;
#pragma unroll 8
  for (int i=iq;i<1024;i+=32)
    acc = fmaf(xs[i], W[(size_t)i*1024 + j], acc);
  red[iq][jq] = acc;
  __syncthreads();
  if (tid < 16){
    float s = 0.f;
#pragma unroll
    for (int ii=0;ii<32;ii++) s += red[ii][tid];
    float S = ssl[0]+ssl[1]+ssl[2]+ssl[3]+ssl[4]+ssl[5]+ssl[6]+ssl[7];
    int jo = blockIdx.x*16 + tid;
    z[jo] = s / S + bv[jo];
  }
}

__global__ __launch_bounds__(512) void hm_mvW1(const float* __restrict__ W,
    const float* __restrict__ z, const float* __restrict__ b1,
    float* __restrict__ hbuf){
  float s = mv_dot<2048>(W, z, threadIdx.x, blockIdx.x);
  int tid = threadIdx.x;
  if (tid < 16){
    int j = blockIdx.x*16 + tid;
    float v = s + b1[j];
    hbuf[j] = 0.5f * v * (1.0f + erff(v * 0.70710678118654752f));
  }
}

__global__ __launch_bounds__(512) void hm_mvW2(const float* __restrict__ W,
    const float* __restrict__ hb, const float* __restrict__ b2,
    float* __restrict__ y){
  float s = mv_dot<1024>(W, hb, threadIdx.x, blockIdx.x);
  int tid = threadIdx.x;
  if (tid < 16){
    int j = blockIdx.x*16 + tid;
    y[j] = s + b2[j];
  }
}

__global__ __launch_bounds__(256) void hm_rms(const float* __restrict__ y,
    const float* __restrict__ scale, float* __restrict__ out){
  __shared__ float red[4];
  __shared__ float msv;
  int tid = threadIdx.x;
  float local = 0.f;
  for (int j=tid;j<1024;j+=256){ float t = y[j]; local = fmaf(t,t,local); }
#pragma unroll
  for (int m=1;m<64;m<<=1) local += __shfl_xor(local, m);
  if ((tid&63)==0) red[tid>>6] = local;
  __syncthreads();
  if (tid==0){
    float s = red[0]+red[1]+red[2]+red[3];
    msv = rsqrtf(s*(1.0f/1024.0f) + 1e-6f);
  }
  __syncthreads();
  float r = msv;
  for (int j=tid;j<1024;j+=256) out[j] = scale[j]*y[j]*r;
}

extern "C" void kernel_launch(void* const* d_in, const int* in_sizes, int n_in,
                              void* d_out, int out_size, void* d_ws, size_t ws_size,
                              hipStream_t stream){
  const float* nodes  = (const float*)d_in[0];
  const float* z_prev = (const float*)d_in[1];
  const float* Wq = (const float*)d_in[2];
  const float* bq = (const float*)d_in[3];
  const float* Wk = (const float*)d_in[4];
  // d_in[5] = bk — cancels in softmax, unused
  const float* Wv = (const float*)d_in[6];
  const float* bv = (const float*)d_in[7];
  const float* W1 = (const float*)d_in[8];
  const float* b1 = (const float*)d_in[9];
  const float* W2 = (const float*)d_in[10];
  const float* b2 = (const float*)d_in[11];
  const float* scale = (const float*)d_in[12];
  float* ws  = (float*)d_ws;
  float* out = (float*)d_out;

  float* Qv   = ws + OQ;
  float* z    = ws + OZ;
  float* hbuf = ws + OH;
  float* ybuf = ws + OY;
  float* sumb = ws + OSUMB;
  unsigned short* qkb = (unsigned short*)(ws + OQKB);
  float* pp2  = ws + OPP2;
  float* pp   = ws + OPP;

  size_t wsf = ws_size/4;
  int nbp = 1;
  if (wsf > (size_t)(OPP + 16384)) nbp = (int)((wsf - OPP)/16384);
  if (nbp > 512) nbp = 512;
  if (nbp < 1) nbp = 1;
  int ny = (nbp + 15)/16;   // <= 32

  const size_t tile_bytes = 16*1028*sizeof(float);  // 65792

  hm_mvQ   <<<64,  512, 0, stream>>>(Wq, z_prev, bq, Qv, z);
  hm_qk2   <<<256, 256, 0, stream>>>(Wk, Qv, qkb);
  hm_fused <<<nbp, 256, tile_bytes, stream>>>(nodes, qkb, pp, sumb);
  hm_predA <<<dim3(64,ny), 256, 0, stream>>>(pp, pp2, nbp);
  hm_mvV   <<<64,  512, 0, stream>>>(Wv, pp2, sumb, bv, z, ny, nbp);
  hm_mvW1  <<<64,  512, 0, stream>>>(W1, z, b1, hbuf);
  hm_mvW2  <<<64,  512, 0, stream>>>(W2, hbuf, b2, ybuf);
  hm_rms   <<<1,   256, 0, stream>>>(ybuf, scale, out);
}

// Round 9
// 89.654 us; speedup vs baseline: 2.9636x; 1.1386x over previous
//
#include <hip/hip_runtime.h>
#include <hip/hip_bf16.h>
#include <math.h>

#define C_N 50000

typedef float f32x16 __attribute__((ext_vector_type(16)));
typedef float f32x4v __attribute__((ext_vector_type(4)));
typedef short bf16x8 __attribute__((ext_vector_type(8)));
typedef unsigned short u16x4 __attribute__((ext_vector_type(4)));
typedef unsigned short u16x2 __attribute__((ext_vector_type(2)));
#define VZERO16 {0.f,0.f,0.f,0.f,0.f,0.f,0.f,0.f,0.f,0.f,0.f,0.f,0.f,0.f,0.f,0.f}

// ---- ws layout (float offsets, all multiples of 16) ----
#define OQ     0        // Q[1024]
#define OZ     1024     // z[2048]
#define OH     3072     // hbuf[1024]
#define OY     4096     // ybuf[1024]
#define OSUMB  5120     // per-block head sums 512*16
#define OQKB   13312    // qkb bf16 B-fragments: 16384 bf16 (8192 floats)
#define OPP2   21504    // 2nd-level pool partials, bf16: 32*16384 ushort = 262144 float-slots
#define OPP    283648   // pool partials, bf16: nb*16384 ushort

__device__ __forceinline__ int brev4(int l){
  return ((l&1)<<3)|((l&2)<<1)|((l&4)>>1)|((l&8)>>3);
}

__device__ __forceinline__ float bf2f(unsigned short u){
  unsigned int x = ((unsigned int)u)<<16;
  return __builtin_bit_cast(float, x);
}

// Sum 16 values (f32x16) over 64 lanes; lanes l<16 get total for head brev4(l).
__device__ __forceinline__ float vred16(f32x16 v, int lane){
  float send, got;
#define RS(A,B,M) \
  send = (lane&M)? v[A] : v[B]; \
  got  = __shfl_xor(send, M);   \
  v[A] = ((lane&M)? v[B] : v[A]) + got;
  RS(0,8,1) RS(1,9,1) RS(2,10,1) RS(3,11,1)
  RS(4,12,1) RS(5,13,1) RS(6,14,1) RS(7,15,1)
  RS(0,4,2) RS(1,5,2) RS(2,6,2) RS(3,7,2)
  RS(0,2,4) RS(1,3,4)
  RS(0,1,8)
#undef RS
  float t = v[0];
  t += __shfl_xor(t,16);
  t += __shfl_xor(t,32);
  return t;
}

// ---- 16-output matvec block, NT threads: out_j = sum_i x[i]*W[i*1024+j] ----
template<int IN, int NT>
__device__ __forceinline__ float mv_dot(const float* __restrict__ W,
    const float* __restrict__ x, int tid, int jblk){
  __shared__ float xs[IN];
  __shared__ float red[NT/16][17];
  for (int k=tid;k<IN;k+=NT) xs[k]=x[k];
  __syncthreads();
  int jq = tid&15, iq = tid>>4;        // NT/16 i-groups x 16 j
  int j = jblk*16 + jq;
  float acc = 0.f;
#pragma unroll 8
  for (int i=iq;i<IN;i+=NT/16)
    acc = fmaf(xs[i], W[(size_t)i*1024 + j], acc);
  red[iq][jq] = acc;
  __syncthreads();
  float s = 0.f;
  if (tid < 16){
#pragma unroll
    for (int ii=0;ii<NT/16;ii++) s += red[ii][tid];
  }
  return s;
}

// Q = z_prev@Wq + bq; also copy z_prev into z[1024:2048]
__global__ __launch_bounds__(1024) void hm_mvQ(const float* __restrict__ W,
    const float* __restrict__ x, const float* __restrict__ bq,
    float* __restrict__ Q, float* __restrict__ z){
  float s = mv_dot<1024,1024>(W, x, threadIdx.x, blockIdx.x);
  int tid = threadIdx.x;
  int j0 = blockIdx.x*16;
  if (tid < 16){
    Q[j0+tid] = s + bq[j0+tid];
    z[1024 + j0 + tid] = x[j0 + tid];
  }
}

// qk[i][h] = sum_t Wk[i][h*64+t]*Q[h*64+t]; one wave per row i.
// Writes DIRECTLY in bf16 MFMA B-fragment order:
// flat bf16 idx = (kc*64 + rg*16 + h)*8 + jj with kc=i>>5, rg=(i>>3)&3, jj=i&7.
__global__ __launch_bounds__(256) void hm_qk2(const float* __restrict__ Wk,
    const float* __restrict__ Q, unsigned short* __restrict__ qkb){
  __shared__ float qlds[1024];
  int tid = threadIdx.x;
  for (int k=tid;k<1024;k+=256) qlds[k]=Q[k];
  __syncthreads();
  int w = tid>>6, l = tid&63;
  int i = blockIdx.x*4 + w;
  const float* wr = Wk + (size_t)i*1024 + l;
  f32x16 acc = VZERO16;
#define QKS(k) acc[k] = wr[k*64] * qlds[k*64 + l];
  QKS(0) QKS(1) QKS(2) QKS(3) QKS(4) QKS(5) QKS(6) QKS(7)
  QKS(8) QKS(9) QKS(10) QKS(11) QKS(12) QKS(13) QKS(14) QKS(15)
#undef QKS
  float t = vred16(acc, l);
  if (l < 16){
    int h = brev4(l);
    int kc = i>>5, rg = (i>>3)&3, jj = i&7;
    __hip_bfloat16 b = __float2bfloat16(t);
    qkb[(kc*64 + rg*16 + h)*8 + jj] = *(unsigned short*)&b;
  }
}

#define LD2(AP,KC,FA,FB) \
  FA = *(const float4*)((AP)+(KC)*32); \
  FB = *(const float4*)((AP)+(KC)*32+4);
#define CVT8(FA,FB,AV) { \
  __hip_bfloat16 c0=__float2bfloat16(FA.x),c1=__float2bfloat16(FA.y); \
  __hip_bfloat16 c2=__float2bfloat16(FA.z),c3=__float2bfloat16(FA.w); \
  __hip_bfloat16 c4=__float2bfloat16(FB.x),c5=__float2bfloat16(FB.y); \
  __hip_bfloat16 c6=__float2bfloat16(FB.z),c7=__float2bfloat16(FB.w); \
  AV[0]=*(short*)&c0; AV[1]=*(short*)&c1; AV[2]=*(short*)&c2; AV[3]=*(short*)&c3; \
  AV[4]=*(short*)&c4; AV[5]=*(short*)&c5; AV[6]=*(short*)&c6; AV[7]=*(short*)&c7; }

// Fused scores(MFMA)+exp+pool with LDS tile staging (single nodes read).
// Partials now written as bf16 (halves WRITE traffic; error ~0.2% relative on
// a pooled value of ~0.004 magnitude — invisible at the 0.0887 threshold).
// launch_bounds(256,2): live ~215 VGPR. 128-cap spilled accs (183us) — keep.
__global__ __launch_bounds__(256,2) void hm_fused(const float* __restrict__ nodes,
    const unsigned short* __restrict__ qkb, unsigned short* __restrict__ parts,
    float* __restrict__ sumpb){
  extern __shared__ float tile[];           // [16][1028]
  __shared__ float part[4][16][17];
  __shared__ float eb[16][16];
  const int tid = threadIdx.x, w = tid>>6, l = tid&63;
  const int rowA = l&15, kgrp = l>>4;
  const int r_ = tid>>4, h_ = tid&15;

  bf16x8 bq0,bq1,bq2,bq3,bq4,bq5,bq6,bq7;
  {
    const bf16x8* qb = (const bf16x8*)qkb;
    const int o = w*8*64 + l;
    bq0=qb[o]; bq1=qb[o+64]; bq2=qb[o+128]; bq3=qb[o+192];
    bq4=qb[o+256]; bq5=qb[o+320]; bq6=qb[o+384]; bq7=qb[o+448];
  }
  f32x16 a0 = VZERO16, a1 = VZERO16, a2 = VZERO16, a3 = VZERO16;
  float ssum = 0.f;
  const int stride = gridDim.x;

  int cb = blockIdx.x;
  float4 p0a,p0b,p1a,p1b,p2a,p2b,p3a,p3b,p4a,p4b,p5a,p5b,p6a,p6b,p7a,p7b;
  {
    const float* ap = nodes + ((size_t)(cb*16 + rowA))*1024 + w*256 + kgrp*8;
    LD2(ap,0,p0a,p0b) LD2(ap,1,p1a,p1b) LD2(ap,2,p2a,p2b) LD2(ap,3,p3a,p3b)
    LD2(ap,4,p4a,p4b) LD2(ap,5,p5a,p5b) LD2(ap,6,p6a,p6b) LD2(ap,7,p7a,p7b)
  }
  float* tw = tile + rowA*1028 + w*256 + kgrp*8;

  for (; cb < 3125; cb += stride){
    __syncthreads();                       // barrier0: prev tile fully read
    *(float4*)(tw+0*32) = p0a; *(float4*)(tw+0*32+4) = p0b;
    *(float4*)(tw+1*32) = p1a; *(float4*)(tw+1*32+4) = p1b;
    *(float4*)(tw+2*32) = p2a; *(float4*)(tw+2*32+4) = p2b;
    *(float4*)(tw+3*32) = p3a; *(float4*)(tw+3*32+4) = p3b;
    *(float4*)(tw+4*32) = p4a; *(float4*)(tw+4*32+4) = p4b;
    *(float4*)(tw+5*32) = p5a; *(float4*)(tw+5*32+4) = p5b;
    *(float4*)(tw+6*32) = p6a; *(float4*)(tw+6*32+4) = p6b;
    *(float4*)(tw+7*32) = p7a; *(float4*)(tw+7*32+4) = p7b;
    bf16x8 av0,av1,av2,av3,av4,av5,av6,av7;
    CVT8(p0a,p0b,av0) CVT8(p1a,p1b,av1) CVT8(p2a,p2b,av2) CVT8(p3a,p3b,av3)
    CVT8(p4a,p4b,av4) CVT8(p5a,p5b,av5) CVT8(p6a,p6b,av6) CVT8(p7a,p7b,av7)
    f32x4v D0 = {0.f,0.f,0.f,0.f};
    f32x4v D1 = {0.f,0.f,0.f,0.f};
    D0 = __builtin_amdgcn_mfma_f32_16x16x32_bf16(av0, bq0, D0, 0,0,0);
    D1 = __builtin_amdgcn_mfma_f32_16x16x32_bf16(av1, bq1, D1, 0,0,0);
    D0 = __builtin_amdgcn_mfma_f32_16x16x32_bf16(av2, bq2, D0, 0,0,0);
    D1 = __builtin_amdgcn_mfma_f32_16x16x32_bf16(av3, bq3, D1, 0,0,0);
    D0 = __builtin_amdgcn_mfma_f32_16x16x32_bf16(av4, bq4, D0, 0,0,0);
    D1 = __builtin_amdgcn_mfma_f32_16x16x32_bf16(av5, bq5, D1, 0,0,0);
    D0 = __builtin_amdgcn_mfma_f32_16x16x32_bf16(av6, bq6, D0, 0,0,0);
    D1 = __builtin_amdgcn_mfma_f32_16x16x32_bf16(av7, bq7, D1, 0,0,0);
    {
      int cbn = cb + stride; if (cbn >= 3125) cbn = cb;
      const float* apn = nodes + ((size_t)(cbn*16 + rowA))*1024 + w*256 + kgrp*8;
      LD2(apn,0,p0a,p0b) LD2(apn,1,p1a,p1b) LD2(apn,2,p2a,p2b) LD2(apn,3,p3a,p3b)
      LD2(apn,4,p4a,p4b) LD2(apn,5,p5a,p5b) LD2(apn,6,p6a,p6b) LD2(apn,7,p7a,p7b)
    }
#pragma unroll
    for (int i=0;i<4;i++) part[w][kgrp*4+i][rowA] = D0[i] + D1[i];
    __syncthreads();                       // barrier1
    {
      float s = part[0][r_][h_]+part[1][r_][h_]+part[2][r_][h_]+part[3][r_][h_];
      eb[r_][h_] = __expf(s * 0.125f);
    }
    __syncthreads();                       // barrier2
    if (tid < 16){
#pragma unroll
      for (int rr=0;rr<16;rr++) ssum += eb[rr][tid];
    }
    const float* tr = tile + w*256 + l*4;
#pragma unroll 4
    for (int r=0;r<16;r++){
      float4 nv = *(const float4*)(tr + r*1028);
      f32x16 u = *(const f32x16*)&eb[r][0];
      a0 += u*nv.x; a1 += u*nv.y; a2 += u*nv.z; a3 += u*nv.w;
    }
  }
  // epilogue: bf16 partials
  unsigned short* p = parts + (size_t)blockIdx.x*16384 + w*256 + l*4;
#pragma unroll
  for (int h=0;h<16;h++){
    __hip_bfloat16 b0=__float2bfloat16(a0[h]), b1=__float2bfloat16(a1[h]);
    __hip_bfloat16 b2=__float2bfloat16(a2[h]), b3=__float2bfloat16(a3[h]);
    u16x4 o;
    o[0]=*(unsigned short*)&b0; o[1]=*(unsigned short*)&b1;
    o[2]=*(unsigned short*)&b2; o[3]=*(unsigned short*)&b3;
    *(u16x4*)(p + h*1024) = o;
  }
  if (tid < 16) sumpb[blockIdx.x*16 + tid] = ssum;
}

// Stage A: pp2[y][j] = sum of 16 bf16 partials (fully parallel, BW-bound)
__global__ __launch_bounds__(256) void hm_predA(const unsigned short* __restrict__ parts,
    unsigned short* __restrict__ pp2, int nb){
  int j2 = blockIdx.x*256 + threadIdx.x;   // handles 2 j's (ushort2)
  int b0 = blockIdx.y*16;
  int b1 = b0+16 < nb ? b0+16 : nb;
  float s0 = 0.f, s1 = 0.f;
  for (int b=b0;b<b1;b++){
    u16x2 v = *(const u16x2*)&parts[(size_t)b*16384 + j2*2];
    s0 += bf2f(v[0]); s1 += bf2f(v[1]);
  }
  __hip_bfloat16 r0=__float2bfloat16(s0), r1=__float2bfloat16(s1);
  u16x2 o; o[0]=*(unsigned short*)&r0; o[1]=*(unsigned short*)&r1;
  *(u16x2*)&pp2[(size_t)blockIdx.y*16384 + j2*2] = o;
}

// z[j] = (Pu[h]·Wv[:,j])/S[h] + bv[j]; Pu row hh summed from bf16 pp2
// in-kernel; S[h] reduced inline from sumpb. 1024 threads.
__global__ __launch_bounds__(1024) void hm_mvV(const float* __restrict__ W,
    const unsigned short* __restrict__ pp2, const float* __restrict__ sumpb,
    const float* __restrict__ bv, float* __restrict__ z, int ny, int nb){
  __shared__ float xs[1024];
  __shared__ float red[64][17];
  __shared__ float ssl[16];
  const int tid = threadIdx.x;
  const int hh = blockIdx.x>>2;
  float sacc = 0.f;
  for (int b=tid; b<nb; b+=1024) sacc += sumpb[b*16 + hh];
#pragma unroll
  for (int m=1;m<64;m<<=1) sacc += __shfl_xor(sacc, m);
  if ((tid&63)==0) ssl[tid>>6] = sacc;
  {
    int k = tid;
    float s = 0.f;
    for (int y=0;y<ny;y++) s += bf2f(pp2[(size_t)y*16384 + hh*1024 + k]);
    xs[k] = s;
  }
  __syncthreads();
  int jq = tid&15, iq = tid>>4;
  int j = blockIdx.x*16 + jq;
  float acc = 0.f;
#pragma unroll 8
  for (int i=iq;i<1024;i+=64)
    acc = fmaf(xs[i], W[(size_t)i*1024 + j], acc);
  red[iq][jq] = acc;
  __syncthreads();
  if (tid < 16){
    float s = 0.f;
#pragma unroll
    for (int ii=0;ii<64;ii++) s += red[ii][tid];
    float S = 0.f;
#pragma unroll
    for (int q=0;q<16;q++) S += ssl[q];
    int jo = blockIdx.x*16 + tid;
    z[jo] = s / S + bv[jo];
  }
}

__global__ __launch_bounds__(1024) void hm_mvW1(const float* __restrict__ W,
    const float* __restrict__ z, const float* __restrict__ b1,
    float* __restrict__ hbuf){
  float s = mv_dot<2048,1024>(W, z, threadIdx.x, blockIdx.x);
  int tid = threadIdx.x;
  if (tid < 16){
    int j = blockIdx.x*16 + tid;
    float v = s + b1[j];
    hbuf[j] = 0.5f * v * (1.0f + erff(v * 0.70710678118654752f));
  }
}

__global__ __launch_bounds__(1024) void hm_mvW2(const float* __restrict__ W,
    const float* __restrict__ hb, const float* __restrict__ b2,
    float* __restrict__ y){
  float s = mv_dot<1024,1024>(W, hb, threadIdx.x, blockIdx.x);
  int tid = threadIdx.x;
  if (tid < 16){
    int j = blockIdx.x*16 + tid;
    y[j] = s + b2[j];
  }
}

__global__ __launch_bounds__(256) void hm_rms(const float* __restrict__ y,
    const float* __restrict__ scale, float* __restrict__ out){
  __shared__ float red[4];
  __shared__ float msv;
  int tid = threadIdx.x;
  float local = 0.f;
  for (int j=tid;j<1024;j+=256){ float t = y[j]; local = fmaf(t,t,local); }
#pragma unroll
  for (int m=1;m<64;m<<=1) local += __shfl_xor(local, m);
  if ((tid&63)==0) red[tid>>6] = local;
  __syncthreads();
  if (tid==0){
    float s = red[0]+red[1]+red[2]+red[3];
    msv = rsqrtf(s*(1.0f/1024.0f) + 1e-6f);
  }
  __syncthreads();
  float r = msv;
  for (int j=tid;j<1024;j+=256) out[j] = scale[j]*y[j]*r;
}

extern "C" void kernel_launch(void* const* d_in, const int* in_sizes, int n_in,
                              void* d_out, int out_size, void* d_ws, size_t ws_size,
                              hipStream_t stream){
  const float* nodes  = (const float*)d_in[0];
  const float* z_prev = (const float*)d_in[1];
  const float* Wq = (const float*)d_in[2];
  const float* bq = (const float*)d_in[3];
  const float* Wk = (const float*)d_in[4];
  // d_in[5] = bk — cancels in softmax, unused
  const float* Wv = (const float*)d_in[6];
  const float* bv = (const float*)d_in[7];
  const float* W1 = (const float*)d_in[8];
  const float* b1 = (const float*)d_in[9];
  const float* W2 = (const float*)d_in[10];
  const float* b2 = (const float*)d_in[11];
  const float* scale = (const float*)d_in[12];
  float* ws  = (float*)d_ws;
  float* out = (float*)d_out;

  float* Qv   = ws + OQ;
  float* z    = ws + OZ;
  float* hbuf = ws + OH;
  float* ybuf = ws + OY;
  float* sumb = ws + OSUMB;
  unsigned short* qkb = (unsigned short*)(ws + OQKB);
  unsigned short* pp2 = (unsigned short*)(ws + OPP2);
  unsigned short* pp  = (unsigned short*)(ws + OPP);

  size_t need0 = (size_t)OPP*4;
  int nbp = 1;
  if (ws_size > need0 + 32768) nbp = (int)((ws_size - need0)/32768);
  if (nbp > 512) nbp = 512;
  if (nbp < 1) nbp = 1;
  int ny = (nbp + 15)/16;   // <= 32

  const size_t tile_bytes = 16*1028*sizeof(float);  // 65792

  hm_mvQ   <<<64,  1024, 0, stream>>>(Wq, z_prev, bq, Qv, z);
  hm_qk2   <<<256, 256, 0, stream>>>(Wk, Qv, qkb);
  hm_fused <<<nbp, 256, tile_bytes, stream>>>(nodes, qkb, pp, sumb);
  hm_predA <<<dim3(32,ny), 256, 0, stream>>>(pp, pp2, nbp);
  hm_mvV   <<<64,  1024, 0, stream>>>(Wv, pp2, sumb, bv, z, ny, nbp);
  hm_mvW1  <<<64,  1024, 0, stream>>>(W1, z, b1, hbuf);
  hm_mvW2  <<<64,  1024, 0, stream>>>(W2, hbuf, b2, ybuf);
  hm_rms   <<<1,   256, 0, stream>>>(ybuf, scale, out);
}